// Round 2
// baseline (623.457 us; speedup 1.0000x reference)
//
#include <hip/hip_runtime.h>

#define NROWS    262144   // 16 * 16384
#define DIMS     64
#define KCODES   512
#define MTILE    32       // rows per block (was 64; halved to shrink acc/thread)
#define RPW      4        // rows per wave
#define CHUNK    256      // cols per LDS chunk
#define NCHUNK   2
#define NTHREADS 512

// ---------------------------------------------------------------------------
// prep: embedT[k][d] = embed[d][k]; enorm[k] = sum_d embed[d][k]^2 (numpy
// pairwise-8 order); zero the likelihood accumulator.
// grid <<<512, 64>>> : block = one code k, lane = d.
// ---------------------------------------------------------------------------
__global__ void prep_kernel(const float* __restrict__ embed,
                            float* __restrict__ embedT,
                            float* __restrict__ enorm,
                            float* __restrict__ lik) {
    int k = blockIdx.x;
    int d = threadIdx.x;
    float v = embed[d * KCODES + k];
    embedT[k * DIMS + d] = v;
    float sq = __fmul_rn(v, v);
    // numpy pairwise: r_j = sq_j + sq_{j+8} + ... (sequential), j = d & 7
    int j = d & 7;
    float r = __shfl(sq, j, 64);
#pragma unroll
    for (int i = 1; i < 8; ++i)
        r = __fadd_rn(r, __shfl(sq, j + 8 * i, 64));
    // combine ((r0+r1)+(r2+r3)) + ((r4+r5)+(r6+r7)) via xor tree (bitwise exact)
    float t;
    t = __shfl_xor(r, 1, 64); r = __fadd_rn(r, t);
    t = __shfl_xor(r, 2, 64); r = __fadd_rn(r, t);
    t = __shfl_xor(r, 4, 64); r = __fadd_rn(r, t);
    if (d == 0) { enorm[k] = r; lik[k] = 0.0f; }
}

// ---------------------------------------------------------------------------
// main: fused GEMM (dot of each row with all 512 codes) + softmax + argmax +
// hard-gather write + likelihood partial accumulation.
// grid <<<8192, 512>>>. Block: 32 rows x 512 cols.
// Thread (cg = tid&63, rg = tid>>6): 4 rows (rg*4..) x 4 cols (cg*4..) per
// 256-col chunk -> acc[2][4][4] = 32 VGPRs. Wave = one rg = 4 full rows
// (in-wave softmax; col->lane mapping identical to the 8-row version, so all
// wave-reduction orders are bit-identical).
//
// WHY 4 rows/wave: the 8-row version needed acc[2][8][4]=64 live floats +
// 16 e-regs + x regs ≈ 95+, but the allocator pinned VGPR_Count=64 (both
// __launch_bounds__(512,4) and amdgpu_waves_per_eu(4) failed to lift it),
// spilling ~36 floats/thread to scratch: WRITE_SIZE showed 352 MB = 64 MB out
// + 288 MiB (= 2M threads * 144 B) of spill writebacks, VALUBusy 48%.
// Halving rows/thread makes the live set ~64-80 regs -> no spill is possible
// at any plausible allocation. LDS stays 64 KB -> still 2 blocks/CU.
// ---------------------------------------------------------------------------
__launch_bounds__(NTHREADS)
__global__ void main_kernel(const float* __restrict__ x,
                            const float* __restrict__ embed,
                            const float* __restrict__ sigma,
                            const float* __restrict__ embedT,
                            const float* __restrict__ enorm,
                            float* __restrict__ lik,
                            float* __restrict__ out) {
    __shared__ float e_lds[DIMS * CHUNK];   // 64 KB exactly

    const int tid = threadIdx.x;
    const int cg  = tid & 63;        // col group (4 cols)
    const int rg  = tid >> 6;        // row group (4 rows), == wave id
    const int rowbase = blockIdx.x * MTILE + rg * RPW;

    const float sigma_v = sigma[0];

    float acc[NCHUNK][RPW][4];
#pragma unroll
    for (int c = 0; c < NCHUNK; ++c)
#pragma unroll
        for (int r = 0; r < RPW; ++r)
#pragma unroll
            for (int q = 0; q < 4; ++q) acc[c][r][q] = 0.0f;

    const float4* __restrict__ x4  = reinterpret_cast<const float4*>(x);
    const float4* __restrict__ eg4 = reinterpret_cast<const float4*>(embed);

#pragma unroll
    for (int ch = 0; ch < NCHUNK; ++ch) {
        __syncthreads();   // protect previous chunk's readers
        // stage embed chunk: wave-contiguous rows (one d-row per wave-iter)
#pragma unroll
        for (int i = 0; i < 8; ++i) {
            int f4 = tid + i * NTHREADS;          // 0..4095
            int d  = f4 >> 6;
            int c4 = f4 & 63;
            reinterpret_cast<float4*>(e_lds)[d * 64 + c4] =
                eg4[d * 128 + ch * 64 + c4];
        }
        __syncthreads();

        const float4* e4 = reinterpret_cast<const float4*>(e_lds);
#pragma unroll 2
        for (int d = 0; d < DIMS; d += 4) {
            float4 e0 = e4[(d + 0) * 64 + cg];
            float4 e1 = e4[(d + 1) * 64 + cg];
            float4 e2 = e4[(d + 2) * 64 + cg];
            float4 e3 = e4[(d + 3) * 64 + cg];
            int d4 = d >> 2;
#pragma unroll
            for (int r = 0; r < RPW; ++r) {
                float4 xv = x4[(rowbase + r) * 16 + d4];
                // ascending-d sequential fma chain per (r,col)
                acc[ch][r][0] = fmaf(xv.x, e0.x, acc[ch][r][0]);
                acc[ch][r][1] = fmaf(xv.x, e0.y, acc[ch][r][1]);
                acc[ch][r][2] = fmaf(xv.x, e0.z, acc[ch][r][2]);
                acc[ch][r][3] = fmaf(xv.x, e0.w, acc[ch][r][3]);
                acc[ch][r][0] = fmaf(xv.y, e1.x, acc[ch][r][0]);
                acc[ch][r][1] = fmaf(xv.y, e1.y, acc[ch][r][1]);
                acc[ch][r][2] = fmaf(xv.y, e1.z, acc[ch][r][2]);
                acc[ch][r][3] = fmaf(xv.y, e1.w, acc[ch][r][3]);
                acc[ch][r][0] = fmaf(xv.z, e2.x, acc[ch][r][0]);
                acc[ch][r][1] = fmaf(xv.z, e2.y, acc[ch][r][1]);
                acc[ch][r][2] = fmaf(xv.z, e2.z, acc[ch][r][2]);
                acc[ch][r][3] = fmaf(xv.z, e2.w, acc[ch][r][3]);
                acc[ch][r][0] = fmaf(xv.w, e3.x, acc[ch][r][0]);
                acc[ch][r][1] = fmaf(xv.w, e3.y, acc[ch][r][1]);
                acc[ch][r][2] = fmaf(xv.w, e3.z, acc[ch][r][2]);
                acc[ch][r][3] = fmaf(xv.w, e3.w, acc[ch][r][3]);
            }
        }
    }

    // ---- xnorm for the wave's 4 rows, numpy pairwise-8 order ----
    // lane cg = r_l*8 + j_l computes partial r_{j_l} of row (r_l & 3); the
    // upper 32 lanes duplicate rows 0-3 (keeps the 8-lane xor tree bit-exact
    // and avoids reading rows outside this wave's ownership).
    const int r_l = (cg >> 3) & 3;
    const int j_l = cg & 7;
    float xr;
    {
        const float* xp = x + (size_t)(rowbase + r_l) * DIMS + j_l;
        float v0 = xp[0];
        float s = __fmul_rn(v0, v0);
#pragma unroll
        for (int i = 1; i < 8; ++i) {
            float v = xp[8 * i];
            s = __fadd_rn(s, __fmul_rn(v, v));
        }
        xr = s;
    }
    {
        float t;
        t = __shfl_xor(xr, 1, 64); xr = __fadd_rn(xr, t);
        t = __shfl_xor(xr, 2, 64); xr = __fadd_rn(xr, t);
        t = __shfl_xor(xr, 4, 64); xr = __fadd_rn(xr, t);
    }
    // lane r*8+j now holds xnorm of row r (r = 0..3)

    // enorm for this thread's 8 cols
    float en[NCHUNK][4];
#pragma unroll
    for (int c = 0; c < NCHUNK; ++c)
#pragma unroll
        for (int q = 0; q < 4; ++q)
            en[c][q] = enorm[c * CHUNK + cg * 4 + q];

    float likpart[NCHUNK][4];
#pragma unroll
    for (int c = 0; c < NCHUNK; ++c)
#pragma unroll
        for (int q = 0; q < 4; ++q) likpart[c][q] = 0.0f;

#pragma unroll
    for (int r = 0; r < RPW; ++r) {
        float xn = __shfl(xr, r * 8, 64);
        // z = -sigma * ((xnorm - 2*dot) + enorm), np-assembly order.
        // IN-PLACE: z overwrites acc[c][r][q] (dot is dead afterwards).
        float m = -INFINITY;
#pragma unroll
        for (int c = 0; c < NCHUNK; ++c)
#pragma unroll
            for (int q = 0; q < 4; ++q) {
                float dot  = acc[c][r][q];
                float td   = __fsub_rn(xn, __fmul_rn(2.0f, dot));
                float dist = __fadd_rn(td, en[c][q]);
                float zz   = __fmul_rn(-sigma_v, dist);
                acc[c][r][q] = zz;
                m = fmaxf(m, zz);
            }
#pragma unroll
        for (int mask = 1; mask < 64; mask <<= 1)
            m = fmaxf(m, __shfl_xor(m, mask, 64));

        // ev overwrites z in place
        float s = 0.0f;
        float bv = -1.0f;
        int   bc = KCODES;
#pragma unroll
        for (int c = 0; c < NCHUNK; ++c)
#pragma unroll
            for (int q = 0; q < 4; ++q) {
                float ee = expf(__fsub_rn(acc[c][r][q], m));
                acc[c][r][q] = ee;
                s += ee;
                int col = c * CHUNK + cg * 4 + q;
                if (ee > bv) { bv = ee; bc = col; }   // first-index tiebreak
            }
#pragma unroll
        for (int mask = 1; mask < 64; mask <<= 1)
            s += __shfl_xor(s, mask, 64);
#pragma unroll
        for (int mask = 1; mask < 64; mask <<= 1) {
            float ov = __shfl_xor(bv, mask, 64);
            int   oc = __shfl_xor(bc, mask, 64);
            if (ov > bv || (ov == bv && oc < bc)) { bv = ov; bc = oc; }
        }

        float invS = 1.0f / s;
#pragma unroll
        for (int c = 0; c < NCHUNK; ++c)
#pragma unroll
            for (int q = 0; q < 4; ++q)
                likpart[c][q] = fmaf(acc[c][r][q], invS, likpart[c][q]);

        // hard-gather write: quantize[row][cg] = embedT[bc][cg]
        // nontemporal: avoid write-allocate RFO on the 64 MB output
        int row = rowbase + r;
        __builtin_nontemporal_store(embedT[bc * DIMS + cg],
                                    &out[(size_t)row * DIMS + cg]);
    }

    // ---- block-level likelihood reduction (reuse e_lds) ----
    float* red = e_lds;
    __syncthreads();
    red[tid] = 0.0f;
    __syncthreads();
#pragma unroll
    for (int c = 0; c < NCHUNK; ++c)
#pragma unroll
        for (int q = 0; q < 4; ++q)
            atomicAdd(&red[c * CHUNK + cg * 4 + q], likpart[c][q]);
    __syncthreads();
    atomicAdd(&lik[tid], red[tid]);
}

// ---------------------------------------------------------------------------
// finish: likelihoods = lik_sum / N; quant_loss = 0.25 * mean(p*(log p - log(l+eps)))
// ---------------------------------------------------------------------------
__global__ void finish_kernel(const float* __restrict__ lik,
                              float* __restrict__ out) {
    int tid = threadIdx.x;   // 512 threads
    float l = lik[tid] / 262144.0f;     // exact: divide by 2^18
    out[16777217 + tid] = l;
    const float p = 1.0f / 512.0f;
    float term = __fmul_rn(p, __fsub_rn(logf(p), logf(l + 1e-10f)));
#pragma unroll
    for (int mask = 1; mask < 64; mask <<= 1)
        term += __shfl_xor(term, mask, 64);
    __shared__ float ws[8];
    if ((tid & 63) == 0) ws[tid >> 6] = term;
    __syncthreads();
    if (tid == 0) {
        float ssum = 0.0f;
        for (int i = 0; i < 8; ++i) ssum += ws[i];
        out[16777216] = 0.25f * (ssum / 512.0f);
    }
}

extern "C" void kernel_launch(void* const* d_in, const int* in_sizes, int n_in,
                              void* d_out, int out_size, void* d_ws, size_t ws_size,
                              hipStream_t stream) {
    const float* x     = (const float*)d_in[0];
    const float* embed = (const float*)d_in[1];
    const float* sigma = (const float*)d_in[2];
    float* out = (float*)d_out;
    float* ws  = (float*)d_ws;

    float* embedT = ws;             // 512*64 = 32768 floats
    float* enorm  = ws + 32768;     // 512 floats
    float* lik    = ws + 33280;     // 512 floats

    prep_kernel<<<KCODES, DIMS, 0, stream>>>(embed, embedT, enorm, lik);
    main_kernel<<<NROWS / MTILE, NTHREADS, 0, stream>>>(x, embed, sigma,
                                                        embedT, enorm, lik, out);
    finish_kernel<<<1, NTHREADS, 0, stream>>>(lik, out);
}

// Round 3
// 553.838 us; speedup vs baseline: 1.1257x; 1.1257x over previous
//
#include <hip/hip_runtime.h>

#define NROWS    262144   // 16 * 16384
#define DIMS     64
#define KCODES   512
#define MTILE    32       // rows per block
#define RPW      4        // rows per wave
#define CHUNK    256      // epilogue col-half width (col->lane ownership, frozen)
#define NCHUNK   2        // col halves per lane (8 cols/lane total, frozen)
#define D_PER    16       // dims per LDS stage  -> 16*512*4 = 32 KB
#define D_CHUNKS 4        // 64 / 16
#define NTHREADS 512

// ---------------------------------------------------------------------------
// prep: embedT[k][d] = embed[d][k]; enorm[k] = sum_d embed[d][k]^2 (numpy
// pairwise-8 order); zero the likelihood accumulator.
// grid <<<512, 64>>> : block = one code k, lane = d.
// ---------------------------------------------------------------------------
__global__ void prep_kernel(const float* __restrict__ embed,
                            float* __restrict__ embedT,
                            float* __restrict__ enorm,
                            float* __restrict__ lik) {
    int k = blockIdx.x;
    int d = threadIdx.x;
    float v = embed[d * KCODES + k];
    embedT[k * DIMS + d] = v;
    float sq = __fmul_rn(v, v);
    // numpy pairwise: r_j = sq_j + sq_{j+8} + ... (sequential), j = d & 7
    int j = d & 7;
    float r = __shfl(sq, j, 64);
#pragma unroll
    for (int i = 1; i < 8; ++i)
        r = __fadd_rn(r, __shfl(sq, j + 8 * i, 64));
    // combine ((r0+r1)+(r2+r3)) + ((r4+r5)+(r6+r7)) via xor tree (bitwise exact)
    float t;
    t = __shfl_xor(r, 1, 64); r = __fadd_rn(r, t);
    t = __shfl_xor(r, 2, 64); r = __fadd_rn(r, t);
    t = __shfl_xor(r, 4, 64); r = __fadd_rn(r, t);
    if (d == 0) { enorm[k] = r; lik[k] = 0.0f; }
}

// ---------------------------------------------------------------------------
// main: fused GEMM + softmax + argmax + hard-gather + likelihood partials.
// grid <<<8192, 512>>>. Block: 32 rows x 512 cols.
// Thread (cg = tid&63, rg = tid>>6): 4 rows x 8 cols (cols c*256 + cg*4 + q,
// c in {0,1}) -> acc[2][4][4] = 32 VGPRs. Wave = 4 full rows (in-wave softmax).
//
// ROUND-3 CHANGE: LDS staging is chunked over DIMS (4 stages of
// e[16 d][512 cols] = 32 KB) instead of over columns (64 KB). Col->lane
// ownership and every reduction order are unchanged; per-output fma operand
// sequence is still strictly ascending d -> bit-identical results. 32 KB LDS
// lifts residency from 2 to 4 blocks/CU (16 -> 32 waves/CU): round-2 counters
// showed a latency-bound kernel (VALUBusy 45%, HBM 2.4%, Occupancy 45.6%) —
// doubling waves/SIMD is the lever. Live set: acc 32 + e 16 + xv 2 + addr
// ~= 60 VGPR (each x/e address loaded exactly once -> no CSE blow-up).
// ---------------------------------------------------------------------------
__launch_bounds__(NTHREADS)
__global__ void main_kernel(const float* __restrict__ x,
                            const float* __restrict__ embed,
                            const float* __restrict__ sigma,
                            const float* __restrict__ embedT,
                            const float* __restrict__ enorm,
                            float* __restrict__ lik,
                            float* __restrict__ out) {
    __shared__ float e_lds[D_PER * KCODES];   // 32 KB

    const int tid = threadIdx.x;
    const int cg  = tid & 63;        // col group (4 cols per half)
    const int rg  = tid >> 6;        // row group (4 rows), == wave id
    const int rowbase = blockIdx.x * MTILE + rg * RPW;

    const float sigma_v = sigma[0];

    float acc[NCHUNK][RPW][4];
#pragma unroll
    for (int c = 0; c < NCHUNK; ++c)
#pragma unroll
        for (int r = 0; r < RPW; ++r)
#pragma unroll
            for (int q = 0; q < 4; ++q) acc[c][r][q] = 0.0f;

    const float2* __restrict__ x2  = reinterpret_cast<const float2*>(x);
    const float4* __restrict__ eg4 = reinterpret_cast<const float4*>(embed);
    float4* e_lds4 = reinterpret_cast<float4*>(e_lds);

    for (int dc = 0; dc < D_CHUNKS; ++dc) {
        __syncthreads();   // protect previous stage's readers
        // stage e[dc*16 .. dc*16+15][0..511]: perfectly linear float4 copy
#pragma unroll
        for (int i = 0; i < 4; ++i) {
            int f4 = tid + i * NTHREADS;          // 0..2047
            e_lds4[f4] = eg4[dc * (D_PER * KCODES / 4) + f4];
        }
        __syncthreads();

        const float4* e4 = reinterpret_cast<const float4*>(e_lds);
#pragma unroll 2
        for (int d2 = 0; d2 < D_PER / 2; ++d2) {     // dim pairs within stage
            // e rows for dims (2*d2, 2*d2+1), both col halves (4 cols each)
            float4 e0a = e4[(2 * d2 + 0) * 128 +  0 + cg];   // dim lo, half 0
            float4 e1a = e4[(2 * d2 + 1) * 128 +  0 + cg];   // dim hi, half 0
            float4 e0b = e4[(2 * d2 + 0) * 128 + 64 + cg];   // dim lo, half 1
            float4 e1b = e4[(2 * d2 + 1) * 128 + 64 + cg];   // dim hi, half 1
            int d2g = dc * (D_PER / 2) + d2;                 // global dim-pair
#pragma unroll
            for (int r = 0; r < RPW; ++r) {
                float2 xv = x2[(size_t)(rowbase + r) * 32 + d2g];
                // ascending-d sequential fma chain per (r,col) — bit-exact
                acc[0][r][0] = fmaf(xv.x, e0a.x, acc[0][r][0]);
                acc[0][r][1] = fmaf(xv.x, e0a.y, acc[0][r][1]);
                acc[0][r][2] = fmaf(xv.x, e0a.z, acc[0][r][2]);
                acc[0][r][3] = fmaf(xv.x, e0a.w, acc[0][r][3]);
                acc[0][r][0] = fmaf(xv.y, e1a.x, acc[0][r][0]);
                acc[0][r][1] = fmaf(xv.y, e1a.y, acc[0][r][1]);
                acc[0][r][2] = fmaf(xv.y, e1a.z, acc[0][r][2]);
                acc[0][r][3] = fmaf(xv.y, e1a.w, acc[0][r][3]);
                acc[1][r][0] = fmaf(xv.x, e0b.x, acc[1][r][0]);
                acc[1][r][1] = fmaf(xv.x, e0b.y, acc[1][r][1]);
                acc[1][r][2] = fmaf(xv.x, e0b.z, acc[1][r][2]);
                acc[1][r][3] = fmaf(xv.x, e0b.w, acc[1][r][3]);
                acc[1][r][0] = fmaf(xv.y, e1b.x, acc[1][r][0]);
                acc[1][r][1] = fmaf(xv.y, e1b.y, acc[1][r][1]);
                acc[1][r][2] = fmaf(xv.y, e1b.z, acc[1][r][2]);
                acc[1][r][3] = fmaf(xv.y, e1b.w, acc[1][r][3]);
            }
        }
    }

    // ---- xnorm for the wave's 4 rows, numpy pairwise-8 order ----
    // lane cg = r_l*8 + j_l computes partial r_{j_l} of row (r_l & 3); the
    // upper 32 lanes duplicate rows 0-3 (keeps the 8-lane xor tree bit-exact
    // and avoids reading rows outside this wave's ownership).
    const int r_l = (cg >> 3) & 3;
    const int j_l = cg & 7;
    float xr;
    {
        const float* xp = x + (size_t)(rowbase + r_l) * DIMS + j_l;
        float v0 = xp[0];
        float s = __fmul_rn(v0, v0);
#pragma unroll
        for (int i = 1; i < 8; ++i) {
            float v = xp[8 * i];
            s = __fadd_rn(s, __fmul_rn(v, v));
        }
        xr = s;
    }
    {
        float t;
        t = __shfl_xor(xr, 1, 64); xr = __fadd_rn(xr, t);
        t = __shfl_xor(xr, 2, 64); xr = __fadd_rn(xr, t);
        t = __shfl_xor(xr, 4, 64); xr = __fadd_rn(xr, t);
    }
    // lane r*8+j now holds xnorm of row r (r = 0..3)

    // enorm for this thread's 8 cols
    float en[NCHUNK][4];
#pragma unroll
    for (int c = 0; c < NCHUNK; ++c)
#pragma unroll
        for (int q = 0; q < 4; ++q)
            en[c][q] = enorm[c * CHUNK + cg * 4 + q];

    float likpart[NCHUNK][4];
#pragma unroll
    for (int c = 0; c < NCHUNK; ++c)
#pragma unroll
        for (int q = 0; q < 4; ++q) likpart[c][q] = 0.0f;

#pragma unroll
    for (int r = 0; r < RPW; ++r) {
        float xn = __shfl(xr, r * 8, 64);
        // z = -sigma * ((xnorm - 2*dot) + enorm), np-assembly order.
        // IN-PLACE: z overwrites acc[c][r][q] (dot is dead afterwards).
        float m = -INFINITY;
#pragma unroll
        for (int c = 0; c < NCHUNK; ++c)
#pragma unroll
            for (int q = 0; q < 4; ++q) {
                float dot  = acc[c][r][q];
                float td   = __fsub_rn(xn, __fmul_rn(2.0f, dot));
                float dist = __fadd_rn(td, en[c][q]);
                float zz   = __fmul_rn(-sigma_v, dist);
                acc[c][r][q] = zz;
                m = fmaxf(m, zz);
            }
#pragma unroll
        for (int mask = 1; mask < 64; mask <<= 1)
            m = fmaxf(m, __shfl_xor(m, mask, 64));

        // ev overwrites z in place
        float s = 0.0f;
        float bv = -1.0f;
        int   bc = KCODES;
#pragma unroll
        for (int c = 0; c < NCHUNK; ++c)
#pragma unroll
            for (int q = 0; q < 4; ++q) {
                float ee = expf(__fsub_rn(acc[c][r][q], m));
                acc[c][r][q] = ee;
                s += ee;
                int col = c * CHUNK + cg * 4 + q;
                if (ee > bv) { bv = ee; bc = col; }   // first-index tiebreak
            }
#pragma unroll
        for (int mask = 1; mask < 64; mask <<= 1)
            s += __shfl_xor(s, mask, 64);
#pragma unroll
        for (int mask = 1; mask < 64; mask <<= 1) {
            float ov = __shfl_xor(bv, mask, 64);
            int   oc = __shfl_xor(bc, mask, 64);
            if (ov > bv || (ov == bv && oc < bc)) { bv = ov; bc = oc; }
        }

        float invS = 1.0f / s;
#pragma unroll
        for (int c = 0; c < NCHUNK; ++c)
#pragma unroll
            for (int q = 0; q < 4; ++q)
                likpart[c][q] = fmaf(acc[c][r][q], invS, likpart[c][q]);

        // hard-gather write: quantize[row][cg] = embedT[bc][cg]
        // nontemporal: avoid write-allocate RFO on the 64 MB output
        int row = rowbase + r;
        __builtin_nontemporal_store(embedT[bc * DIMS + cg],
                                    &out[(size_t)row * DIMS + cg]);
    }

    // ---- block-level likelihood reduction (reuse e_lds) ----
    float* red = e_lds;
    __syncthreads();
    red[tid] = 0.0f;
    __syncthreads();
#pragma unroll
    for (int c = 0; c < NCHUNK; ++c)
#pragma unroll
        for (int q = 0; q < 4; ++q)
            atomicAdd(&red[c * CHUNK + cg * 4 + q], likpart[c][q]);
    __syncthreads();
    atomicAdd(&lik[tid], red[tid]);
}

// ---------------------------------------------------------------------------
// finish: likelihoods = lik_sum / N; quant_loss = 0.25 * mean(p*(log p - log(l+eps)))
// ---------------------------------------------------------------------------
__global__ void finish_kernel(const float* __restrict__ lik,
                              float* __restrict__ out) {
    int tid = threadIdx.x;   // 512 threads
    float l = lik[tid] / 262144.0f;     // exact: divide by 2^18
    out[16777217 + tid] = l;
    const float p = 1.0f / 512.0f;
    float term = __fmul_rn(p, __fsub_rn(logf(p), logf(l + 1e-10f)));
#pragma unroll
    for (int mask = 1; mask < 64; mask <<= 1)
        term += __shfl_xor(term, mask, 64);
    __shared__ float ws[8];
    if ((tid & 63) == 0) ws[tid >> 6] = term;
    __syncthreads();
    if (tid == 0) {
        float ssum = 0.0f;
        for (int i = 0; i < 8; ++i) ssum += ws[i];
        out[16777216] = 0.25f * (ssum / 512.0f);
    }
}

extern "C" void kernel_launch(void* const* d_in, const int* in_sizes, int n_in,
                              void* d_out, int out_size, void* d_ws, size_t ws_size,
                              hipStream_t stream) {
    const float* x     = (const float*)d_in[0];
    const float* embed = (const float*)d_in[1];
    const float* sigma = (const float*)d_in[2];
    float* out = (float*)d_out;
    float* ws  = (float*)d_ws;

    float* embedT = ws;             // 512*64 = 32768 floats
    float* enorm  = ws + 32768;     // 512 floats
    float* lik    = ws + 33280;     // 512 floats

    prep_kernel<<<KCODES, DIMS, 0, stream>>>(embed, embedT, enorm, lik);
    main_kernel<<<NROWS / MTILE, NTHREADS, 0, stream>>>(x, embed, sigma,
                                                        embedT, enorm, lik, out);
    finish_kernel<<<1, NTHREADS, 0, stream>>>(lik, out);
}